// Round 7
// baseline (959.458 us; speedup 1.0000x reference)
//
#include <hip/hip_runtime.h>
#include <math.h>

#define B_   2
#define S_   3072
#define C_   256
#define NH   8
#define HD   32
#define HALF 16
#define NELEM (B_*S_*C_)   // 1,572,864
#define MLROWS (B_*NH*S_)  // 49,152 rows per split

__device__ __forceinline__ float dot4(float4 a, float4 b) {
    return a.x*b.x + a.y*b.y + a.z*b.z + a.w*b.w;
}

// ---------------- GEMM: out[M x 256] = (A[M x 256] @ W[256 x 256]^T (+bias))*scl ---
// 64x64 tile, 256 threads, 4x4 microtile, K staged in 32-wide chunks.
__device__ __forceinline__ void gemm_nt_body(const float* __restrict__ A,
                                             const float* __restrict__ W,
                                             const float* __restrict__ bias,
                                             float* __restrict__ out,
                                             float scl)
{
    __shared__ float As[64][36];   // +4 pad keeps float4 alignment, breaks some conflicts
    __shared__ float Ws[64][36];
    const int tid  = threadIdx.x;
    const int tx4  = (tid & 15) * 4;   // col group
    const int ty4  = (tid >> 4) * 4;   // row group
    const int row0 = blockIdx.x * 64;
    const int col0 = blockIdx.y * 64;

    float acc[4][4] = {};

    for (int kc = 0; kc < C_; kc += 32) {
        __syncthreads();
        #pragma unroll
        for (int l = tid; l < 512; l += 256) {
            const int r  = l >> 3;
            const int k4 = (l & 7) * 4;
            *(float4*)&As[r][k4] = *(const float4*)&A[(size_t)(row0 + r)*C_ + kc + k4];
            *(float4*)&Ws[r][k4] = *(const float4*)&W[(size_t)(col0 + r)*C_ + kc + k4];
        }
        __syncthreads();
        #pragma unroll
        for (int k4 = 0; k4 < 32; k4 += 4) {
            float4 a0 = *(const float4*)&As[ty4+0][k4];
            float4 a1 = *(const float4*)&As[ty4+1][k4];
            float4 a2 = *(const float4*)&As[ty4+2][k4];
            float4 a3 = *(const float4*)&As[ty4+3][k4];
            float4 w0 = *(const float4*)&Ws[tx4+0][k4];
            float4 w1 = *(const float4*)&Ws[tx4+1][k4];
            float4 w2 = *(const float4*)&Ws[tx4+2][k4];
            float4 w3 = *(const float4*)&Ws[tx4+3][k4];
            acc[0][0] += dot4(a0,w0); acc[0][1] += dot4(a0,w1);
            acc[0][2] += dot4(a0,w2); acc[0][3] += dot4(a0,w3);
            acc[1][0] += dot4(a1,w0); acc[1][1] += dot4(a1,w1);
            acc[1][2] += dot4(a1,w2); acc[1][3] += dot4(a1,w3);
            acc[2][0] += dot4(a2,w0); acc[2][1] += dot4(a2,w1);
            acc[2][2] += dot4(a2,w2); acc[2][3] += dot4(a2,w3);
            acc[3][0] += dot4(a3,w0); acc[3][1] += dot4(a3,w1);
            acc[3][2] += dot4(a3,w2); acc[3][3] += dot4(a3,w3);
        }
    }

    float4 bv = make_float4(0.f, 0.f, 0.f, 0.f);
    if (bias) bv = *(const float4*)&bias[col0 + tx4];
    #pragma unroll
    for (int rr = 0; rr < 4; ++rr) {
        float4 o = make_float4((acc[rr][0] + bv.x)*scl, (acc[rr][1] + bv.y)*scl,
                               (acc[rr][2] + bv.z)*scl, (acc[rr][3] + bv.w)*scl);
        *(float4*)&out[(size_t)(row0 + ty4 + rr)*C_ + col0 + tx4] = o;
    }
}

__global__ __launch_bounds__(256) void qkv_kernel(
        const float* __restrict__ x,
        const float* __restrict__ Wq, const float* __restrict__ Wk, const float* __restrict__ Wv,
        const float* __restrict__ qb, const float* __restrict__ vb,
        float* __restrict__ q, float* __restrict__ k, float* __restrict__ v)
{
    // scale 1/sqrt(32) folded into q projection (RoPE rotation commutes with scalar)
    if      (blockIdx.z == 0) gemm_nt_body(x, Wq, qb,      q, 0.17677669529663687f);
    else if (blockIdx.z == 1) gemm_nt_body(x, Wk, nullptr, k, 1.0f);
    else                      gemm_nt_body(x, Wv, vb,      v, 1.0f);
}

__global__ __launch_bounds__(256) void out_gemm_kernel(
        const float* __restrict__ ctx, const float* __restrict__ Wo,
        const float* __restrict__ bo, float* __restrict__ out)
{
    gemm_nt_body(ctx, Wo, bo, out, 1.0f);
}

// ---------------- RoPE (in place on q and k), phase in double --------------------
__global__ __launch_bounds__(256) void rope_kernel(float* __restrict__ q, float* __restrict__ k)
{
    const int idx = blockIdx.x * 256 + threadIdx.x;   // grid sized exactly
    const int per_tensor = B_ * S_ * NH * HALF;       // 786432
    float* t = (idx < per_tensor) ? q : k;
    const int i   = (idx < per_tensor) ? idx : idx - per_tensor;
    const int j   = i & 15;
    const int hh  = (i >> 4) & 7;
    const int row = i >> 7;                            // 0 .. B_*S_-1
    const int s   = (row >= S_) ? (row - S_) : row;    // position within batch

    const double invf = exp(-log(10000.0) * (double)j * (1.0 / 16.0));
    // match reference: angle formed in fp32, then accurate sin/cos of that angle
    const float  angf = (float)((double)s * invf);
    double sn, cs;
    sincos((double)angf, &sn, &cs);
    const float c = (float)cs, sf = (float)sn;

    const size_t base = (size_t)row * C_ + hh * HD + j;
    const float t1 = t[base];
    const float t2 = t[base + HALF];
    t[base]        = t1 * c - t2 * sf;
    t[base + HALF] = t2 * c + t1 * sf;
}

// ---------------- Flash attention, fp32, scalar-broadcast K/V ---------------------
// ONE WAVE per block, ONE q-row per LANE (64 rows/block). Cols iterate
// sequentially in 32-col chunks; for each col, K[c][0..31] / V[c][0..31] is
// WAVE-UNIFORM -> the compiler emits s_load (SMEM pipe) into SGPRs, and the
// FMA is v_fmac_f32 v_acc, s_kv, v_q (1 SGPR operand). Consequences:
//   - ZERO LDS traffic (R5/R6 were LDS-return-bus bound: 128KB/wave-tile
//     through 128B/clk/CU capped VALUBusy at ~53-57%)
//   - zero barriers, zero shuffles (softmax fully lane-local), near-zero
//     address VALU (scalar addressing on the SALU pipe)
//   - VGPR = qreg32 + sc32 + acc32 + temps ~= 120 -> 4 waves/SIMD
// Split-KV (NSPLIT) raises the grid to 3072 independent waves = 12/CU to
// cover s_load latency; partial results merged by combine_kernel.
template<int NSPLIT>
__global__ __launch_bounds__(64) void attn_kernel(
        const float* __restrict__ q, const float* __restrict__ k,
        const float* __restrict__ v, float* __restrict__ outp,
        float* __restrict__ pm, float* __restrict__ pl)
{
    const int lane = threadIdx.x;              // one q-row per lane
    const int qb   = blockIdx.x * 64;
    const int hh   = blockIdx.y;
    const int split = blockIdx.z % NSPLIT;
    const int b     = blockIdx.z / NSPLIT;
    const int kt0   = split * (S_ / NSPLIT);
    const int NC    = S_ / NSPLIT;             // cols this block covers

    const size_t rowbase = (size_t)b * S_;
    const int coloff = hh * HD;
    const int row = qb + lane;

    // q row -> registers (scale already folded into q projection)
    float qreg[32];
    {
        const float* qp = &q[(rowbase + row)*C_ + coloff];
        #pragma unroll
        for (int d4 = 0; d4 < 8; ++d4) {
            float4 t = *(const float4*)&qp[d4*4];
            qreg[d4*4+0]=t.x; qreg[d4*4+1]=t.y; qreg[d4*4+2]=t.z; qreg[d4*4+3]=t.w;
        }
    }

    float m = -1e30f, l = 0.f;
    float acc[32] = {};

    const float* kb = &k[(rowbase + kt0)*C_ + coloff];   // uniform base -> SGPRs
    const float* vb = &v[(rowbase + kt0)*C_ + coloff];

    for (int c0 = 0; c0 < NC; c0 += 32) {
        // ---- scores: 32 cols, K col uniform -> s_load; 4 chains/col for ILP
        float sc[32];
        #pragma unroll
        for (int c = 0; c < 32; ++c) {
            const float* kc = kb + (size_t)(c0 + c)*C_;
            float s0=0.f, s1=0.f, s2=0.f, s3=0.f;
            #pragma unroll
            for (int d4 = 0; d4 < 8; ++d4) {
                s0 = fmaf(qreg[d4*4+0], kc[d4*4+0], s0);
                s1 = fmaf(qreg[d4*4+1], kc[d4*4+1], s1);
                s2 = fmaf(qreg[d4*4+2], kc[d4*4+2], s2);
                s3 = fmaf(qreg[d4*4+3], kc[d4*4+3], s3);
            }
            sc[c] = (s0 + s1) + (s2 + s3);
        }

        // ---- lane-local online softmax (no shuffles: lane owns its full row)
        {
            float t16[16];
            #pragma unroll
            for (int i = 0; i < 16; ++i) t16[i] = fmaxf(sc[i], sc[i+16]);
            #pragma unroll
            for (int i = 0; i < 8; ++i)  t16[i] = fmaxf(t16[i], t16[i+8]);
            #pragma unroll
            for (int i = 0; i < 4; ++i)  t16[i] = fmaxf(t16[i], t16[i+4]);
            const float tm = fmaxf(fmaxf(t16[0], t16[2]), fmaxf(t16[1], t16[3]));

            const float mnew = fmaxf(m, tm);
            const float f = __expf(m - mnew);
            m = mnew; l *= f;
            #pragma unroll
            for (int d = 0; d < 32; ++d) acc[d] *= f;
            #pragma unroll
            for (int c = 0; c < 32; ++c) sc[c] = __expf(sc[c] - mnew);

            float s16[16];
            #pragma unroll
            for (int i = 0; i < 16; ++i) s16[i] = sc[i] + sc[i+16];
            #pragma unroll
            for (int i = 0; i < 8; ++i)  s16[i] = s16[i] + s16[i+8];
            #pragma unroll
            for (int i = 0; i < 4; ++i)  s16[i] = s16[i] + s16[i+4];
            l += (s16[0] + s16[2]) + (s16[1] + s16[3]);
        }

        // ---- PV: V col uniform -> s_load; 32 independent acc chains (ILP over d)
        #pragma unroll
        for (int c = 0; c < 32; ++c) {
            const float* vc = vb + (size_t)(c0 + c)*C_;
            const float p = sc[c];
            #pragma unroll
            for (int d = 0; d < 32; ++d)
                acc[d] = fmaf(p, vc[d], acc[d]);
        }
    }

    if (NSPLIT == 1) {
        const float invl = 1.f / l;
        float* ob = outp + (rowbase + row)*C_ + coloff;
        #pragma unroll
        for (int d4 = 0; d4 < 8; ++d4) {
            float4 o = make_float4(acc[d4*4+0]*invl, acc[d4*4+1]*invl,
                                   acc[d4*4+2]*invl, acc[d4*4+3]*invl);
            *(float4*)&ob[d4*4] = o;
        }
    } else {
        float* ob = outp + (size_t)split*NELEM + (rowbase + row)*C_ + coloff;
        #pragma unroll
        for (int d4 = 0; d4 < 8; ++d4) {
            float4 o = make_float4(acc[d4*4+0], acc[d4*4+1], acc[d4*4+2], acc[d4*4+3]);
            *(float4*)&ob[d4*4] = o;
        }
        const size_t mlb = (size_t)split*MLROWS + ((size_t)b*NH + hh)*S_;
        pm[mlb + row] = m;          // lane-contiguous -> coalesced
        pl[mlb + row] = l;
    }
}

// ---------------- combine the NSPLIT KV-split partials ---------------------------
// One thread per float4 of ctx; pacc slabs are NELEM apart, pm/pl MLROWS apart.
template<int NSPLIT>
__global__ __launch_bounds__(256) void combine_kernel(
        const float* __restrict__ pacc, const float* __restrict__ pm,
        const float* __restrict__ pl, float* __restrict__ ctx)
{
    const int gid = blockIdx.x * 256 + threadIdx.x;   // 0 .. B_*S_*NH*8-1
    int rem = gid >> 3;                               // drop d4
    const int h = rem & 7; rem >>= 3;
    const int s = rem % S_;
    const int b = rem / S_;

    const size_t i0 = ((size_t)b*NH + h)*S_ + s;
    float mm[NSPLIT], ll[NSPLIT], w[NSPLIT];
    float M = -1e30f;
    #pragma unroll
    for (int i = 0; i < NSPLIT; ++i) {
        mm[i] = pm[i0 + (size_t)i*MLROWS];
        ll[i] = pl[i0 + (size_t)i*MLROWS];
        M = fmaxf(M, mm[i]);
    }
    float L = 0.f;
    #pragma unroll
    for (int i = 0; i < NSPLIT; ++i) { w[i] = __expf(mm[i] - M); L += ll[i]*w[i]; }
    const float invL = 1.f / L;

    const size_t a = (size_t)gid * 4;                 // linear float4 address
    float4 o = make_float4(0.f, 0.f, 0.f, 0.f);
    #pragma unroll
    for (int i = 0; i < NSPLIT; ++i) {
        const float4 x = *(const float4*)&pacc[a + (size_t)i*NELEM];
        o.x += x.x*w[i]; o.y += x.y*w[i]; o.z += x.z*w[i]; o.w += x.w*w[i];
    }
    o.x *= invL; o.y *= invL; o.z *= invL; o.w *= invL;
    *(float4*)&ctx[a] = o;
}

// ---------------- launch ---------------------------------------------------------
extern "C" void kernel_launch(void* const* d_in, const int* in_sizes, int n_in,
                              void* d_out, int out_size, void* d_ws, size_t ws_size,
                              hipStream_t stream)
{
    const float* x  = (const float*)d_in[0];
    const float* Wq = (const float*)d_in[1];
    const float* Wk = (const float*)d_in[2];
    const float* Wv = (const float*)d_in[3];
    const float* qb = (const float*)d_in[4];
    const float* vb = (const float*)d_in[5];
    const float* Wo = (const float*)d_in[6];
    const float* bo = (const float*)d_in[7];
    float* out = (float*)d_out;

    float* ws  = (float*)d_ws;
    float* q   = ws;
    float* k   = q + NELEM;
    float* v   = k + NELEM;
    float* ctx = v + NELEM;
    float* pacc = ctx + NELEM;                         // NSPLIT x NELEM

    const size_t need4 = ((size_t)(4+4)*NELEM + (size_t)2*4*MLROWS) * sizeof(float);
    const size_t need2 = ((size_t)(4+2)*NELEM + (size_t)2*2*MLROWS) * sizeof(float);

    // q,k,v projections (+bias, q pre-scaled), 64x64 tiles
    qkv_kernel<<<dim3(96, 4, 3), 256, 0, stream>>>(x, Wq, Wk, Wv, qb, vb, q, k, v);
    // RoPE in place on q and k
    rope_kernel<<<6144, 256, 0, stream>>>(q, k);

    if (ws_size >= need4) {
        float* pm = pacc + (size_t)4*NELEM;
        float* pl = pm + (size_t)4*MLROWS;
        attn_kernel<4><<<dim3(S_/64, NH, B_*4), 64, 0, stream>>>(q, k, v, pacc, pm, pl);
        combine_kernel<4><<<(B_*S_*NH*8)/256, 256, 0, stream>>>(pacc, pm, pl, ctx);
    } else if (ws_size >= need2) {
        float* pm = pacc + (size_t)2*NELEM;
        float* pl = pm + (size_t)2*MLROWS;
        attn_kernel<2><<<dim3(S_/64, NH, B_*2), 64, 0, stream>>>(q, k, v, pacc, pm, pl);
        combine_kernel<2><<<(B_*S_*NH*8)/256, 256, 0, stream>>>(pacc, pm, pl, ctx);
    } else {
        attn_kernel<1><<<dim3(S_/64, NH, B_), 64, 0, stream>>>(q, k, v, ctx, nullptr, nullptr);
    }

    // output projection
    out_gemm_kernel<<<dim3(96, 4, 1), 256, 0, stream>>>(ctx, Wo, bo, out);
}

// Round 8
// 646.793 us; speedup vs baseline: 1.4834x; 1.4834x over previous
//
#include <hip/hip_runtime.h>
#include <math.h>

#define B_   2
#define S_   3072
#define C_   256
#define NH   8
#define HD   32
#define HALF 16
#define NELEM (B_*S_*C_)   // 1,572,864
#define MLROWS (B_*NH*S_)  // 49,152 rows per split

__device__ __forceinline__ float dot4(float4 a, float4 b) {
    return a.x*b.x + a.y*b.y + a.z*b.z + a.w*b.w;
}

// direct global->LDS copy, 16B per lane; LDS dest is wave-uniform base + lane*16
__device__ __forceinline__ void gload_lds16(const float* g, float* l) {
    __builtin_amdgcn_global_load_lds(
        (const __attribute__((address_space(1))) unsigned int*)g,
        (__attribute__((address_space(3))) unsigned int*)l, 16, 0, 0);
}

// ---------------- GEMM: out[M x 256] = (A[M x 256] @ W[256 x 256]^T (+bias))*scl ---
__device__ __forceinline__ void gemm_nt_body(const float* __restrict__ A,
                                             const float* __restrict__ W,
                                             const float* __restrict__ bias,
                                             float* __restrict__ out,
                                             float scl)
{
    __shared__ float As[64][36];
    __shared__ float Ws[64][36];
    const int tid  = threadIdx.x;
    const int tx4  = (tid & 15) * 4;
    const int ty4  = (tid >> 4) * 4;
    const int row0 = blockIdx.x * 64;
    const int col0 = blockIdx.y * 64;

    float acc[4][4] = {};

    for (int kc = 0; kc < C_; kc += 32) {
        __syncthreads();
        #pragma unroll
        for (int l = tid; l < 512; l += 256) {
            const int r  = l >> 3;
            const int k4 = (l & 7) * 4;
            *(float4*)&As[r][k4] = *(const float4*)&A[(size_t)(row0 + r)*C_ + kc + k4];
            *(float4*)&Ws[r][k4] = *(const float4*)&W[(size_t)(col0 + r)*C_ + kc + k4];
        }
        __syncthreads();
        #pragma unroll
        for (int k4 = 0; k4 < 32; k4 += 4) {
            float4 a0 = *(const float4*)&As[ty4+0][k4];
            float4 a1 = *(const float4*)&As[ty4+1][k4];
            float4 a2 = *(const float4*)&As[ty4+2][k4];
            float4 a3 = *(const float4*)&As[ty4+3][k4];
            float4 w0 = *(const float4*)&Ws[tx4+0][k4];
            float4 w1 = *(const float4*)&Ws[tx4+1][k4];
            float4 w2 = *(const float4*)&Ws[tx4+2][k4];
            float4 w3 = *(const float4*)&Ws[tx4+3][k4];
            acc[0][0] += dot4(a0,w0); acc[0][1] += dot4(a0,w1);
            acc[0][2] += dot4(a0,w2); acc[0][3] += dot4(a0,w3);
            acc[1][0] += dot4(a1,w0); acc[1][1] += dot4(a1,w1);
            acc[1][2] += dot4(a1,w2); acc[1][3] += dot4(a1,w3);
            acc[2][0] += dot4(a2,w0); acc[2][1] += dot4(a2,w1);
            acc[2][2] += dot4(a2,w2); acc[2][3] += dot4(a2,w3);
            acc[3][0] += dot4(a3,w0); acc[3][1] += dot4(a3,w1);
            acc[3][2] += dot4(a3,w2); acc[3][3] += dot4(a3,w3);
        }
    }

    float4 bv = make_float4(0.f, 0.f, 0.f, 0.f);
    if (bias) bv = *(const float4*)&bias[col0 + tx4];
    #pragma unroll
    for (int rr = 0; rr < 4; ++rr) {
        float4 o = make_float4((acc[rr][0] + bv.x)*scl, (acc[rr][1] + bv.y)*scl,
                               (acc[rr][2] + bv.z)*scl, (acc[rr][3] + bv.w)*scl);
        *(float4*)&out[(size_t)(row0 + ty4 + rr)*C_ + col0 + tx4] = o;
    }
}

__global__ __launch_bounds__(256) void qkv_kernel(
        const float* __restrict__ x,
        const float* __restrict__ Wq, const float* __restrict__ Wk, const float* __restrict__ Wv,
        const float* __restrict__ qb, const float* __restrict__ vb,
        float* __restrict__ q, float* __restrict__ k, float* __restrict__ v)
{
    // scale 1/sqrt(32) folded into q projection (RoPE rotation commutes with scalar)
    if      (blockIdx.z == 0) gemm_nt_body(x, Wq, qb,      q, 0.17677669529663687f);
    else if (blockIdx.z == 1) gemm_nt_body(x, Wk, nullptr, k, 1.0f);
    else                      gemm_nt_body(x, Wv, vb,      v, 1.0f);
}

__global__ __launch_bounds__(256) void out_gemm_kernel(
        const float* __restrict__ ctx, const float* __restrict__ Wo,
        const float* __restrict__ bo, float* __restrict__ out)
{
    gemm_nt_body(ctx, Wo, bo, out, 1.0f);
}

// ---------------- RoPE (in place on q and k), phase in double --------------------
__global__ __launch_bounds__(256) void rope_kernel(float* __restrict__ q, float* __restrict__ k)
{
    const int idx = blockIdx.x * 256 + threadIdx.x;
    const int per_tensor = B_ * S_ * NH * HALF;       // 786432
    float* t = (idx < per_tensor) ? q : k;
    const int i   = (idx < per_tensor) ? idx : idx - per_tensor;
    const int j   = i & 15;
    const int hh  = (i >> 4) & 7;
    const int row = i >> 7;
    const int s   = (row >= S_) ? (row - S_) : row;

    const double invf = exp(-log(10000.0) * (double)j * (1.0 / 16.0));
    const float  angf = (float)((double)s * invf);
    double sn, cs;
    sincos((double)angf, &sn, &cs);
    const float c = (float)cs, sf = (float)sn;

    const size_t base = (size_t)row * C_ + hh * HD + j;
    const float t1 = t[base];
    const float t2 = t[base + HALF];
    t[base]        = t1 * c - t2 * sf;
    t[base + HALF] = t2 * c + t1 * sf;
}

// ---------------- softmax helpers: tree reductions (short dep chains) -------------
__device__ __forceinline__ float tree_max8(const float s[8]) {
    float t0 = fmaxf(s[0], s[4]), t1 = fmaxf(s[1], s[5]);
    float t2 = fmaxf(s[2], s[6]), t3 = fmaxf(s[3], s[7]);
    return fmaxf(fmaxf(t0, t2), fmaxf(t1, t3));
}
__device__ __forceinline__ float tree_sum8(const float s[8]) {
    float t0 = s[0] + s[4], t1 = s[1] + s[5];
    float t2 = s[2] + s[6], t3 = s[3] + s[7];
    return (t0 + t2) + (t1 + t3);
}

// ---------------- Flash attention, fp32, split-KV, r=3 rows/lane ------------------
// 1 wave (64 thr) per block, 48 q-rows: group g = tid>>2 owns rows qb+g+{0,16,32};
// sub = tid&3 splits the 32 kv-cols 4 ways (8 cols/lane). r=3 raises FMAs per
// ds_read_b128 from 8 to 12: chip ds_read count 18.9M -> 12.6M (the binding pipe:
// R5/R6 showed the LDS return bus caps this kernel; R7 showed SMEM broadcast
// can't replace it). No barriers (1 wave): counted vmcnt pipeline only.
//
// LDS swizzle (mandatory per R6: linear layout = 4-way conflict, 7.5e7 cycles):
// physical col4 p of row r holds logical col4 p^(r&3); staged by pre-swizzling
// the GLOBAL source column (global_load_lds writes LDS linearly). Reads XOR with
// sub (= r&3, loop-invariant per lane -> hoisted). 4 lanes of an instr hit 4
// distinct bank quads, 16-lane broadcast each -> conflict-free.
//
// grid (S_/48, NH, B_*NSPLIT) = 2048 blocks -> exactly 8 resident/CU
// (LDS 16KB*8 = 128KB, VGPR ~240 -> 2 waves/SIMD).
template<int NSPLIT>
__global__ __launch_bounds__(64) void attn_kernel(
        const float* __restrict__ q, const float* __restrict__ k,
        const float* __restrict__ v, float* __restrict__ outp,
        float* __restrict__ pm, float* __restrict__ pl)
{
    __shared__ float SM[2][2][32*32];   // [buf][0=K,1=V][row*32 + phys col] 16 KB

    const int tid  = threadIdx.x;
    const int sub  = tid & 3;
    const int g    = tid >> 2;                 // 0..15
    const int qb   = blockIdx.x * 48;
    const int hh   = blockIdx.y;
    const int split = blockIdx.z % NSPLIT;
    const int b     = blockIdx.z / NSPLIT;
    const int kt0   = split * (S_ / NSPLIT);
    const int NT    = (S_ / NSPLIT) / 32;      // 48 (split-2) or 96 tiles

    const size_t rowbase = (size_t)b * S_;
    const int coloff = hh * HD;

    // staging: lane covers tile-row srow(+8k); source col pre-swizzled so that
    // LDS physical col4 (tid&7) receives logical col4 (tid&7)^(srow&3)
    const int srow  = tid >> 3;                          // 0..7
    const int sxcol = (((tid & 7) ^ (srow & 3)) << 2);   // swizzled float col
    const float* kstage = &k[(rowbase + kt0 + srow)*C_ + coloff + sxcol];
    const float* vstage = &v[(rowbase + kt0 + srow)*C_ + coloff + sxcol];

    const int r0 = qb + g, r1 = qb + g + 16, r2 = qb + g + 32;

#define ISSUE_TILE(t_, bufi) { \
        const float* gk = kstage + (size_t)(t_)*(32*C_); \
        const float* gv = vstage + (size_t)(t_)*(32*C_); \
        float* lk = &SM[bufi][0][0]; \
        float* lv = &SM[bufi][1][0]; \
        gload_lds16(gk        , lk      ); \
        gload_lds16(gk +  8*C_, lk + 256); \
        gload_lds16(gk + 16*C_, lk + 512); \
        gload_lds16(gk + 24*C_, lk + 768); \
        gload_lds16(gv        , lv      ); \
        gload_lds16(gv +  8*C_, lv + 256); \
        gload_lds16(gv + 16*C_, lv + 512); \
        gload_lds16(gv + 24*C_, lv + 768); }

    // start tile 0 fetch before q-row loads
    ISSUE_TILE(0, 0);

    float q0[32], q1[32], q2[32];              // scale already folded into q
    #pragma unroll
    for (int k4 = 0; k4 < 32; k4 += 4) {
        float4 t0 = *(const float4*)&q[(rowbase + r0)*C_ + coloff + k4];
        float4 t1 = *(const float4*)&q[(rowbase + r1)*C_ + coloff + k4];
        float4 t2 = *(const float4*)&q[(rowbase + r2)*C_ + coloff + k4];
        q0[k4+0]=t0.x; q0[k4+1]=t0.y; q0[k4+2]=t0.z; q0[k4+3]=t0.w;
        q1[k4+0]=t1.x; q1[k4+1]=t1.y; q1[k4+2]=t1.z; q1[k4+3]=t1.w;
        q2[k4+0]=t2.x; q2[k4+1]=t2.y; q2[k4+2]=t2.z; q2[k4+3]=t2.w;
    }

    float m0 = -1e30f, m1 = -1e30f, m2 = -1e30f;
    float l0 = 0.f, l1 = 0.f, l2 = 0.f;
    float a0[32] = {}, a1[32] = {}, a2[32] = {};

    for (int t = 0; t < NT; ++t) {
        const int cur = t & 1;
        if (t + 1 < NT) {
            ISSUE_TILE(t + 1, cur ^ 1);        // async next tile
            asm volatile("s_waitcnt vmcnt(8)" ::: "memory");  // current tile landed
        } else {
            asm volatile("s_waitcnt vmcnt(0)" ::: "memory");
        }
        __builtin_amdgcn_sched_barrier(0);

        const float* Kc = &SM[cur][0][0];
        const float* Vc = &SM[cur][1][0];

        __builtin_amdgcn_s_setprio(1);
        // ---- scores: 8 cols x 3 rows; each K float4 read feeds 12 FMAs
        float s0[8], s1[8], s2[8];
        #pragma unroll
        for (int i = 0; i < 8; ++i) {
            const float* kr = Kc + (sub + 4*i)*32;
            float d0 = 0.f, d1 = 0.f, d2 = 0.f;
            #pragma unroll
            for (int c4 = 0; c4 < 8; ++c4) {
                float4 kk = *(const float4*)&kr[(c4 ^ sub) << 2];
                d0 += q0[c4*4+0]*kk.x + q0[c4*4+1]*kk.y + q0[c4*4+2]*kk.z + q0[c4*4+3]*kk.w;
                d1 += q1[c4*4+0]*kk.x + q1[c4*4+1]*kk.y + q1[c4*4+2]*kk.z + q1[c4*4+3]*kk.w;
                d2 += q2[c4*4+0]*kk.x + q2[c4*4+1]*kk.y + q2[c4*4+2]*kk.z + q2[c4*4+3]*kk.w;
            }
            s0[i] = d0; s1[i] = d1; s2[i] = d2;
        }

        // ---- online softmax, 3 rows (4-lane group shuffles)
        {
            float tm0 = tree_max8(s0), tm1 = tree_max8(s1), tm2 = tree_max8(s2);
            tm0 = fmaxf(tm0, __shfl_xor(tm0, 1)); tm0 = fmaxf(tm0, __shfl_xor(tm0, 2));
            tm1 = fmaxf(tm1, __shfl_xor(tm1, 1)); tm1 = fmaxf(tm1, __shfl_xor(tm1, 2));
            tm2 = fmaxf(tm2, __shfl_xor(tm2, 1)); tm2 = fmaxf(tm2, __shfl_xor(tm2, 2));
            const float mn0 = fmaxf(m0, tm0), mn1 = fmaxf(m1, tm1), mn2 = fmaxf(m2, tm2);
            const float f0 = __expf(m0 - mn0), f1 = __expf(m1 - mn1), f2 = __expf(m2 - mn2);
            m0 = mn0; m1 = mn1; m2 = mn2;
            l0 *= f0; l1 *= f1; l2 *= f2;
            #pragma unroll
            for (int d = 0; d < 32; ++d) { a0[d] *= f0; a1[d] *= f1; a2[d] *= f2; }
            #pragma unroll
            for (int i = 0; i < 8; ++i) {
                s0[i] = __expf(s0[i] - mn0);
                s1[i] = __expf(s1[i] - mn1);
                s2[i] = __expf(s2[i] - mn2);
            }
            l0 += tree_sum8(s0); l1 += tree_sum8(s1); l2 += tree_sum8(s2);
        }

        // ---- PV: each V float4 read feeds 12 FMAs
        #pragma unroll
        for (int i = 0; i < 8; ++i) {
            const float* vr = Vc + (sub + 4*i)*32;
            const float p0 = s0[i], p1 = s1[i], p2 = s2[i];
            #pragma unroll
            for (int d4 = 0; d4 < 8; ++d4) {
                float4 vv = *(const float4*)&vr[(d4 ^ sub) << 2];
                a0[d4*4+0] += p0*vv.x; a0[d4*4+1] += p0*vv.y;
                a0[d4*4+2] += p0*vv.z; a0[d4*4+3] += p0*vv.w;
                a1[d4*4+0] += p1*vv.x; a1[d4*4+1] += p1*vv.y;
                a1[d4*4+2] += p1*vv.z; a1[d4*4+3] += p1*vv.w;
                a2[d4*4+0] += p2*vv.x; a2[d4*4+1] += p2*vv.y;
                a2[d4*4+2] += p2*vv.z; a2[d4*4+3] += p2*vv.w;
            }
        }
        __builtin_amdgcn_s_setprio(0);
    }

#undef ISSUE_TILE

    // ---- reduce across the 4-lane group; normalize only if single-pass
    l0 += __shfl_xor(l0, 1); l0 += __shfl_xor(l0, 2);
    l1 += __shfl_xor(l1, 1); l1 += __shfl_xor(l1, 2);
    l2 += __shfl_xor(l2, 1); l2 += __shfl_xor(l2, 2);
    const float inv0 = (NSPLIT == 1) ? 1.f / l0 : 1.f;
    const float inv1 = (NSPLIT == 1) ? 1.f / l1 : 1.f;
    const float inv2 = (NSPLIT == 1) ? 1.f / l2 : 1.f;
    #pragma unroll
    for (int d = 0; d < 32; ++d) {
        float x0 = a0[d]; x0 += __shfl_xor(x0, 1); x0 += __shfl_xor(x0, 2); a0[d] = x0 * inv0;
        float x1 = a1[d]; x1 += __shfl_xor(x1, 1); x1 += __shfl_xor(x1, 2); a1[d] = x1 * inv1;
        float x2 = a2[d]; x2 += __shfl_xor(x2, 1); x2 += __shfl_xor(x2, 2); a2[d] = x2 * inv2;
    }

    float* obase = (NSPLIT == 1) ? outp : (outp + (size_t)split * NELEM);
    // static-index writes: 4-way branch on sub keeps arrays out of scratch
    #define WRITE_SLICE(ro, a_, off) { \
        float4 o1 = make_float4(a_[(off)+0],a_[(off)+1],a_[(off)+2],a_[(off)+3]); \
        float4 o2 = make_float4(a_[(off)+4],a_[(off)+5],a_[(off)+6],a_[(off)+7]); \
        *(float4*)&obase[(rowbase + (ro))*C_ + coloff + (off)]     = o1; \
        *(float4*)&obase[(rowbase + (ro))*C_ + coloff + (off) + 4] = o2; }
    if      (sub == 0) { WRITE_SLICE(r0, a0, 0)  WRITE_SLICE(r1, a1, 0)  WRITE_SLICE(r2, a2, 0)  }
    else if (sub == 1) { WRITE_SLICE(r0, a0, 8)  WRITE_SLICE(r1, a1, 8)  WRITE_SLICE(r2, a2, 8)  }
    else if (sub == 2) { WRITE_SLICE(r0, a0, 16) WRITE_SLICE(r1, a1, 16) WRITE_SLICE(r2, a2, 16) }
    else               { WRITE_SLICE(r0, a0, 24) WRITE_SLICE(r1, a1, 24) WRITE_SLICE(r2, a2, 24) }
    #undef WRITE_SLICE

    if (NSPLIT > 1 && sub == 0) {
        const size_t mlb = (size_t)split*MLROWS + ((size_t)b*NH + hh)*S_;
        pm[mlb + r0] = m0; pl[mlb + r0] = l0;
        pm[mlb + r1] = m1; pl[mlb + r1] = l1;
        pm[mlb + r2] = m2; pl[mlb + r2] = l2;
    }
}

// ---------------- combine the NSPLIT KV-split partials ---------------------------
template<int NSPLIT>
__global__ __launch_bounds__(256) void combine_kernel(
        const float* __restrict__ pacc, const float* __restrict__ pm,
        const float* __restrict__ pl, float* __restrict__ ctx)
{
    const int gid = blockIdx.x * 256 + threadIdx.x;   // 0 .. B_*S_*NH*8-1
    int rem = gid >> 3;
    const int h = rem & 7; rem >>= 3;
    const int s = rem % S_;
    const int b = rem / S_;

    const size_t i0 = ((size_t)b*NH + h)*S_ + s;
    float mm[NSPLIT], ll[NSPLIT], w[NSPLIT];
    float M = -1e30f;
    #pragma unroll
    for (int i = 0; i < NSPLIT; ++i) {
        mm[i] = pm[i0 + (size_t)i*MLROWS];
        ll[i] = pl[i0 + (size_t)i*MLROWS];
        M = fmaxf(M, mm[i]);
    }
    float L = 0.f;
    #pragma unroll
    for (int i = 0; i < NSPLIT; ++i) { w[i] = __expf(mm[i] - M); L += ll[i]*w[i]; }
    const float invL = 1.f / L;

    const size_t a = (size_t)gid * 4;
    float4 o = make_float4(0.f, 0.f, 0.f, 0.f);
    #pragma unroll
    for (int i = 0; i < NSPLIT; ++i) {
        const float4 x = *(const float4*)&pacc[a + (size_t)i*NELEM];
        o.x += x.x*w[i]; o.y += x.y*w[i]; o.z += x.z*w[i]; o.w += x.w*w[i];
    }
    o.x *= invL; o.y *= invL; o.z *= invL; o.w *= invL;
    *(float4*)&ctx[a] = o;
}

// ---------------- launch ---------------------------------------------------------
extern "C" void kernel_launch(void* const* d_in, const int* in_sizes, int n_in,
                              void* d_out, int out_size, void* d_ws, size_t ws_size,
                              hipStream_t stream)
{
    const float* x  = (const float*)d_in[0];
    const float* Wq = (const float*)d_in[1];
    const float* Wk = (const float*)d_in[2];
    const float* Wv = (const float*)d_in[3];
    const float* qb = (const float*)d_in[4];
    const float* vb = (const float*)d_in[5];
    const float* Wo = (const float*)d_in[6];
    const float* bo = (const float*)d_in[7];
    float* out = (float*)d_out;

    float* ws   = (float*)d_ws;
    float* q    = ws;
    float* k    = q + NELEM;
    float* v    = k + NELEM;
    float* ctx  = v + NELEM;
    float* pacc = ctx + NELEM;                         // NSPLIT x NELEM

    const size_t need2 = ((size_t)(4+2)*NELEM + (size_t)2*2*MLROWS) * sizeof(float);

    // q,k,v projections (+bias, q pre-scaled), 64x64 tiles
    qkv_kernel<<<dim3(96, 4, 3), 256, 0, stream>>>(x, Wq, Wk, Wv, qb, vb, q, k, v);
    // RoPE in place on q and k
    rope_kernel<<<6144, 256, 0, stream>>>(q, k);

    if (ws_size >= need2) {
        float* pm = pacc + (size_t)2*NELEM;
        float* pl = pm + (size_t)2*MLROWS;
        // 2048 single-wave blocks -> 8 resident/CU, 2 waves/SIMD
        attn_kernel<2><<<dim3(S_/48, NH, B_*2), 64, 0, stream>>>(q, k, v, pacc, pm, pl);
        combine_kernel<2><<<(B_*S_*NH*8)/256, 256, 0, stream>>>(pacc, pm, pl, ctx);
    } else {
        attn_kernel<1><<<dim3(S_/48, NH, B_), 64, 0, stream>>>(q, k, v, ctx, nullptr, nullptr);
    }

    // output projection
    out_gemm_kernel<<<dim3(96, 4, 1), 256, 0, stream>>>(ctx, Wo, bo, out);
}

// Round 9
// 491.430 us; speedup vs baseline: 1.9524x; 1.3161x over previous
//
#include <hip/hip_runtime.h>
#include <math.h>

#define B_   2
#define S_   3072
#define C_   256
#define NH   8
#define HD   32
#define HALF 16
#define NELEM (B_*S_*C_)   // 1,572,864
#define MLROWS (B_*NH*S_)  // 49,152 rows per split

__device__ __forceinline__ float dot4(float4 a, float4 b) {
    return a.x*b.x + a.y*b.y + a.z*b.z + a.w*b.w;
}

// direct global->LDS copy, 16B per lane; LDS dest is wave-uniform base + lane*16
__device__ __forceinline__ void gload_lds16(const float* g, float* l) {
    __builtin_amdgcn_global_load_lds(
        (const __attribute__((address_space(1))) unsigned int*)g,
        (__attribute__((address_space(3))) unsigned int*)l, 16, 0, 0);
}

// ---------------- GEMM: out[M x 256] = (A[M x 256] @ W[256 x 256]^T (+bias))*scl ---
__device__ __forceinline__ void gemm_nt_body(const float* __restrict__ A,
                                             const float* __restrict__ W,
                                             const float* __restrict__ bias,
                                             float* __restrict__ out,
                                             float scl)
{
    __shared__ float As[64][36];
    __shared__ float Ws[64][36];
    const int tid  = threadIdx.x;
    const int tx4  = (tid & 15) * 4;
    const int ty4  = (tid >> 4) * 4;
    const int row0 = blockIdx.x * 64;
    const int col0 = blockIdx.y * 64;

    float acc[4][4] = {};

    for (int kc = 0; kc < C_; kc += 32) {
        __syncthreads();
        #pragma unroll
        for (int l = tid; l < 512; l += 256) {
            const int r  = l >> 3;
            const int k4 = (l & 7) * 4;
            *(float4*)&As[r][k4] = *(const float4*)&A[(size_t)(row0 + r)*C_ + kc + k4];
            *(float4*)&Ws[r][k4] = *(const float4*)&W[(size_t)(col0 + r)*C_ + kc + k4];
        }
        __syncthreads();
        #pragma unroll
        for (int k4 = 0; k4 < 32; k4 += 4) {
            float4 a0 = *(const float4*)&As[ty4+0][k4];
            float4 a1 = *(const float4*)&As[ty4+1][k4];
            float4 a2 = *(const float4*)&As[ty4+2][k4];
            float4 a3 = *(const float4*)&As[ty4+3][k4];
            float4 w0 = *(const float4*)&Ws[tx4+0][k4];
            float4 w1 = *(const float4*)&Ws[tx4+1][k4];
            float4 w2 = *(const float4*)&Ws[tx4+2][k4];
            float4 w3 = *(const float4*)&Ws[tx4+3][k4];
            acc[0][0] += dot4(a0,w0); acc[0][1] += dot4(a0,w1);
            acc[0][2] += dot4(a0,w2); acc[0][3] += dot4(a0,w3);
            acc[1][0] += dot4(a1,w0); acc[1][1] += dot4(a1,w1);
            acc[1][2] += dot4(a1,w2); acc[1][3] += dot4(a1,w3);
            acc[2][0] += dot4(a2,w0); acc[2][1] += dot4(a2,w1);
            acc[2][2] += dot4(a2,w2); acc[2][3] += dot4(a2,w3);
            acc[3][0] += dot4(a3,w0); acc[3][1] += dot4(a3,w1);
            acc[3][2] += dot4(a3,w2); acc[3][3] += dot4(a3,w3);
        }
    }

    float4 bv = make_float4(0.f, 0.f, 0.f, 0.f);
    if (bias) bv = *(const float4*)&bias[col0 + tx4];
    #pragma unroll
    for (int rr = 0; rr < 4; ++rr) {
        float4 o = make_float4((acc[rr][0] + bv.x)*scl, (acc[rr][1] + bv.y)*scl,
                               (acc[rr][2] + bv.z)*scl, (acc[rr][3] + bv.w)*scl);
        *(float4*)&out[(size_t)(row0 + ty4 + rr)*C_ + col0 + tx4] = o;
    }
}

__global__ __launch_bounds__(256) void qkv_kernel(
        const float* __restrict__ x,
        const float* __restrict__ Wq, const float* __restrict__ Wk, const float* __restrict__ Wv,
        const float* __restrict__ qb, const float* __restrict__ vb,
        float* __restrict__ q, float* __restrict__ k, float* __restrict__ v)
{
    // scale 1/sqrt(32) folded into q projection (RoPE rotation commutes with scalar)
    if      (blockIdx.z == 0) gemm_nt_body(x, Wq, qb,      q, 0.17677669529663687f);
    else if (blockIdx.z == 1) gemm_nt_body(x, Wk, nullptr, k, 1.0f);
    else                      gemm_nt_body(x, Wv, vb,      v, 1.0f);
}

__global__ __launch_bounds__(256) void out_gemm_kernel(
        const float* __restrict__ ctx, const float* __restrict__ Wo,
        const float* __restrict__ bo, float* __restrict__ out)
{
    gemm_nt_body(ctx, Wo, bo, out, 1.0f);
}

// ---------------- RoPE (in place on q and k), phase in double --------------------
__global__ __launch_bounds__(256) void rope_kernel(float* __restrict__ q, float* __restrict__ k)
{
    const int idx = blockIdx.x * 256 + threadIdx.x;
    const int per_tensor = B_ * S_ * NH * HALF;       // 786432
    float* t = (idx < per_tensor) ? q : k;
    const int i   = (idx < per_tensor) ? idx : idx - per_tensor;
    const int j   = i & 15;
    const int hh  = (i >> 4) & 7;
    const int row = i >> 7;
    const int s   = (row >= S_) ? (row - S_) : row;

    const double invf = exp(-log(10000.0) * (double)j * (1.0 / 16.0));
    const float  angf = (float)((double)s * invf);
    double sn, cs;
    sincos((double)angf, &sn, &cs);
    const float c = (float)cs, sf = (float)sn;

    const size_t base = (size_t)row * C_ + hh * HD + j;
    const float t1 = t[base];
    const float t2 = t[base + HALF];
    t[base]        = t1 * c - t2 * sf;
    t[base + HALF] = t2 * c + t1 * sf;
}

// ---------------- Flash attention, fp32, split-KV, KVBLK=16, 12 waves/CU ----------
// 1 wave (64 thr) per block, 32 q-rows: group g = tid>>2 owns rows qb+g+{0,16};
// sub = tid&3 splits the 16 kv-cols 4 ways (4 cols/lane; 8 FMAs per ds_read_b128).
//
// Why KVBLK=16: LDS/block 8 KB -> the 3072-block grid (96 x 8 x B*2split) is
// FULLY resident: 12 blocks/CU = 12 independent waves = 3 waves/SIMD (VGPR ~140
// fits the 170 cap). R8 showed r=3 at 2 waves/SIMD is latency-bound (both pipes
// ~44%); R5 showed r=2 at ~3 waves/SIMD wins. This keeps r=2 amortization and
// maximizes uncorrelated waves (no barriers, counted vmcnt only).
//
// defer-max (T13, THR=8): skip the acc rescale + l rescale when the whole wave's
// tile max grew <= 8 over the running max (almost always after the first tile on
// N(0,1) scores) — removes the per-tile 64-mult rescale that KVBLK=16 doubled.
//
// LDS source-swizzle (proven R8, 0 conflicts): physical col4 p of row r holds
// logical p^(r&3); reads XOR with sub (= c&3). global_load_lds writes linearly,
// so the permutation is applied on the GLOBAL source address.
template<int NSPLIT>
__global__ __launch_bounds__(64) void attn_kernel(
        const float* __restrict__ q, const float* __restrict__ k,
        const float* __restrict__ v, float* __restrict__ outp,
        float* __restrict__ pm, float* __restrict__ pl)
{
    __shared__ float SM[2][2][16*32];   // [buf][0=K,1=V][row*32 + phys col]  8 KB

    const int tid  = threadIdx.x;
    const int sub  = tid & 3;
    const int g    = tid >> 2;                 // 0..15
    const int qb   = blockIdx.x * 32;
    const int hh   = blockIdx.y;
    const int split = blockIdx.z % NSPLIT;
    const int b     = blockIdx.z / NSPLIT;
    const int kt0   = split * (S_ / NSPLIT);
    const int NT    = (S_ / NSPLIT) / 16;      // 96 (split-2) or 192 tiles

    const size_t rowbase = (size_t)b * S_;
    const int coloff = hh * HD;

    // staging: lane covers tile-rows srow and srow+8; source col pre-swizzled so
    // LDS physical col4 (tid&7) receives logical col4 (tid&7)^(row&3);
    // (srow+8)&3 == srow&3 so one formula serves both gloads.
    const int srow  = tid >> 3;                          // 0..7
    const int sxcol = (((tid & 7) ^ (srow & 3)) << 2);   // swizzled float col
    const float* kstage = &k[(rowbase + kt0 + srow)*C_ + coloff + sxcol];
    const float* vstage = &v[(rowbase + kt0 + srow)*C_ + coloff + sxcol];

    const int r0 = qb + g, r1 = qb + g + 16;

#define ISSUE_TILE(t_, bufi) { \
        const float* gk = kstage + (size_t)(t_)*(16*C_); \
        const float* gv = vstage + (size_t)(t_)*(16*C_); \
        float* lk = &SM[bufi][0][0]; \
        float* lv = &SM[bufi][1][0]; \
        gload_lds16(gk        , lk      ); \
        gload_lds16(gk +  8*C_, lk + 256); \
        gload_lds16(gv        , lv      ); \
        gload_lds16(gv +  8*C_, lv + 256); }

    // start tile 0 fetch before q-row loads
    ISSUE_TILE(0, 0);

    float q0[32], q1[32];                      // scale already folded into q
    #pragma unroll
    for (int k4 = 0; k4 < 32; k4 += 4) {
        float4 t0 = *(const float4*)&q[(rowbase + r0)*C_ + coloff + k4];
        float4 t1 = *(const float4*)&q[(rowbase + r1)*C_ + coloff + k4];
        q0[k4+0]=t0.x; q0[k4+1]=t0.y; q0[k4+2]=t0.z; q0[k4+3]=t0.w;
        q1[k4+0]=t1.x; q1[k4+1]=t1.y; q1[k4+2]=t1.z; q1[k4+3]=t1.w;
    }

    float m0 = -1e30f, m1 = -1e30f;
    float l0 = 0.f, l1 = 0.f;
    float a0[32] = {}, a1[32] = {};

    for (int t = 0; t < NT; ++t) {
        const int cur = t & 1;
        if (t + 1 < NT) {
            ISSUE_TILE(t + 1, cur ^ 1);                       // prefetch next tile
            asm volatile("s_waitcnt vmcnt(4)" ::: "memory");  // tile t landed
        } else {
            asm volatile("s_waitcnt vmcnt(0)" ::: "memory");
        }
        __builtin_amdgcn_sched_barrier(0);

        const float* Kc = &SM[cur][0][0];
        const float* Vc = &SM[cur][1][0];

        __builtin_amdgcn_s_setprio(1);
        // ---- scores: 4 cols x 2 rows; each K float4 read feeds 8 FMAs
        float s0_[4], s1_[4];
        #pragma unroll
        for (int i = 0; i < 4; ++i) {
            const float* kr = Kc + (sub + 4*i)*32;
            float d0 = 0.f, d1 = 0.f;
            #pragma unroll
            for (int c4 = 0; c4 < 8; ++c4) {
                float4 kk = *(const float4*)&kr[(c4 ^ sub) << 2];
                d0 += q0[c4*4+0]*kk.x + q0[c4*4+1]*kk.y + q0[c4*4+2]*kk.z + q0[c4*4+3]*kk.w;
                d1 += q1[c4*4+0]*kk.x + q1[c4*4+1]*kk.y + q1[c4*4+2]*kk.z + q1[c4*4+3]*kk.w;
            }
            s0_[i] = d0; s1_[i] = d1;
        }

        // ---- online softmax with defer-max (T13): rescale only when the wave's
        // tile max grew > 8 over the running max (rare after the first tile)
        {
            float tm0 = fmaxf(fmaxf(s0_[0], s0_[1]), fmaxf(s0_[2], s0_[3]));
            float tm1 = fmaxf(fmaxf(s1_[0], s1_[1]), fmaxf(s1_[2], s1_[3]));
            tm0 = fmaxf(tm0, __shfl_xor(tm0, 1)); tm0 = fmaxf(tm0, __shfl_xor(tm0, 2));
            tm1 = fmaxf(tm1, __shfl_xor(tm1, 1)); tm1 = fmaxf(tm1, __shfl_xor(tm1, 2));
            if (!__all((tm0 - m0 <= 8.f) && (tm1 - m1 <= 8.f))) {
                const float mn0 = fmaxf(m0, tm0), mn1 = fmaxf(m1, tm1);
                const float f0 = __expf(m0 - mn0), f1 = __expf(m1 - mn1);
                m0 = mn0; m1 = mn1;
                l0 *= f0; l1 *= f1;
                #pragma unroll
                for (int d = 0; d < 32; ++d) { a0[d] *= f0; a1[d] *= f1; }
            }
            #pragma unroll
            for (int i = 0; i < 4; ++i) {
                s0_[i] = __expf(s0_[i] - m0);     // bounded by e^8 when deferred
                s1_[i] = __expf(s1_[i] - m1);
            }
            l0 += (s0_[0] + s0_[1]) + (s0_[2] + s0_[3]);
            l1 += (s1_[0] + s1_[1]) + (s1_[2] + s1_[3]);
        }

        // ---- PV: each V float4 read feeds 8 FMAs
        #pragma unroll
        for (int i = 0; i < 4; ++i) {
            const float* vr = Vc + (sub + 4*i)*32;
            const float p0 = s0_[i], p1 = s1_[i];
            #pragma unroll
            for (int d4 = 0; d4 < 8; ++d4) {
                float4 vv = *(const float4*)&vr[(d4 ^ sub) << 2];
                a0[d4*4+0] += p0*vv.x; a0[d4*4+1] += p0*vv.y;
                a0[d4*4+2] += p0*vv.z; a0[d4*4+3] += p0*vv.w;
                a1[d4*4+0] += p1*vv.x; a1[d4*4+1] += p1*vv.y;
                a1[d4*4+2] += p1*vv.z; a1[d4*4+3] += p1*vv.w;
            }
        }
        __builtin_amdgcn_s_setprio(0);
    }

#undef ISSUE_TILE

    // ---- reduce across the 4-lane group; normalize only if single-pass
    l0 += __shfl_xor(l0, 1); l0 += __shfl_xor(l0, 2);
    l1 += __shfl_xor(l1, 1); l1 += __shfl_xor(l1, 2);
    const float inv0 = (NSPLIT == 1) ? 1.f / l0 : 1.f;
    const float inv1 = (NSPLIT == 1) ? 1.f / l1 : 1.f;
    #pragma unroll
    for (int d = 0; d < 32; ++d) {
        float x0 = a0[d]; x0 += __shfl_xor(x0, 1); x0 += __shfl_xor(x0, 2); a0[d] = x0 * inv0;
        float x1 = a1[d]; x1 += __shfl_xor(x1, 1); x1 += __shfl_xor(x1, 2); a1[d] = x1 * inv1;
    }

    float* obase = (NSPLIT == 1) ? outp : (outp + (size_t)split * NELEM);
    // static-index writes: 4-way branch on sub keeps arrays out of scratch
    #define WRITE_SLICE(ro, a_, off) { \
        float4 o1 = make_float4(a_[(off)+0],a_[(off)+1],a_[(off)+2],a_[(off)+3]); \
        float4 o2 = make_float4(a_[(off)+4],a_[(off)+5],a_[(off)+6],a_[(off)+7]); \
        *(float4*)&obase[(rowbase + (ro))*C_ + coloff + (off)]     = o1; \
        *(float4*)&obase[(rowbase + (ro))*C_ + coloff + (off) + 4] = o2; }
    if      (sub == 0) { WRITE_SLICE(r0, a0, 0)  WRITE_SLICE(r1, a1, 0)  }
    else if (sub == 1) { WRITE_SLICE(r0, a0, 8)  WRITE_SLICE(r1, a1, 8)  }
    else if (sub == 2) { WRITE_SLICE(r0, a0, 16) WRITE_SLICE(r1, a1, 16) }
    else               { WRITE_SLICE(r0, a0, 24) WRITE_SLICE(r1, a1, 24) }
    #undef WRITE_SLICE

    if (NSPLIT > 1 && sub == 0) {
        const size_t mlb = (size_t)split*MLROWS + ((size_t)b*NH + hh)*S_;
        pm[mlb + r0] = m0; pl[mlb + r0] = l0;
        pm[mlb + r1] = m1; pl[mlb + r1] = l1;
    }
}

// ---------------- combine the NSPLIT KV-split partials ---------------------------
template<int NSPLIT>
__global__ __launch_bounds__(256) void combine_kernel(
        const float* __restrict__ pacc, const float* __restrict__ pm,
        const float* __restrict__ pl, float* __restrict__ ctx)
{
    const int gid = blockIdx.x * 256 + threadIdx.x;   // 0 .. B_*S_*NH*8-1
    int rem = gid >> 3;
    const int h = rem & 7; rem >>= 3;
    const int s = rem % S_;
    const int b = rem / S_;

    const size_t i0 = ((size_t)b*NH + h)*S_ + s;
    float mm[NSPLIT], ll[NSPLIT], w[NSPLIT];
    float M = -1e30f;
    #pragma unroll
    for (int i = 0; i < NSPLIT; ++i) {
        mm[i] = pm[i0 + (size_t)i*MLROWS];
        ll[i] = pl[i0 + (size_t)i*MLROWS];
        M = fmaxf(M, mm[i]);
    }
    float L = 0.f;
    #pragma unroll
    for (int i = 0; i < NSPLIT; ++i) { w[i] = __expf(mm[i] - M); L += ll[i]*w[i]; }
    const float invL = 1.f / L;

    const size_t a = (size_t)gid * 4;
    float4 o = make_float4(0.f, 0.f, 0.f, 0.f);
    #pragma unroll
    for (int i = 0; i < NSPLIT; ++i) {
        const float4 x = *(const float4*)&pacc[a + (size_t)i*NELEM];
        o.x += x.x*w[i]; o.y += x.y*w[i]; o.z += x.z*w[i]; o.w += x.w*w[i];
    }
    o.x *= invL; o.y *= invL; o.z *= invL; o.w *= invL;
    *(float4*)&ctx[a] = o;
}

// ---------------- launch ---------------------------------------------------------
extern "C" void kernel_launch(void* const* d_in, const int* in_sizes, int n_in,
                              void* d_out, int out_size, void* d_ws, size_t ws_size,
                              hipStream_t stream)
{
    const float* x  = (const float*)d_in[0];
    const float* Wq = (const float*)d_in[1];
    const float* Wk = (const float*)d_in[2];
    const float* Wv = (const float*)d_in[3];
    const float* qb = (const float*)d_in[4];
    const float* vb = (const float*)d_in[5];
    const float* Wo = (const float*)d_in[6];
    const float* bo = (const float*)d_in[7];
    float* out = (float*)d_out;

    float* ws   = (float*)d_ws;
    float* q    = ws;
    float* k    = q + NELEM;
    float* v    = k + NELEM;
    float* ctx  = v + NELEM;
    float* pacc = ctx + NELEM;                         // NSPLIT x NELEM

    const size_t need2 = ((size_t)(4+2)*NELEM + (size_t)2*2*MLROWS) * sizeof(float);

    // q,k,v projections (+bias, q pre-scaled), 64x64 tiles
    qkv_kernel<<<dim3(96, 4, 3), 256, 0, stream>>>(x, Wq, Wk, Wv, qb, vb, q, k, v);
    // RoPE in place on q and k
    rope_kernel<<<6144, 256, 0, stream>>>(q, k);

    if (ws_size >= need2) {
        float* pm = pacc + (size_t)2*NELEM;
        float* pl = pm + (size_t)2*MLROWS;
        // 3072 single-wave blocks -> 12 resident/CU -> 3 waves/SIMD
        attn_kernel<2><<<dim3(S_/32, NH, B_*2), 64, 0, stream>>>(q, k, v, pacc, pm, pl);
        combine_kernel<2><<<(B_*S_*NH*8)/256, 256, 0, stream>>>(pacc, pm, pl, ctx);
    } else {
        attn_kernel<1><<<dim3(S_/32, NH, B_), 64, 0, stream>>>(q, k, v, ctx, nullptr, nullptr);
    }

    // output projection
    out_gemm_kernel<<<dim3(96, 4, 1), 256, 0, stream>>>(ctx, Wo, bo, out);
}